// Round 8
// baseline (149.260 us; speedup 1.0000x reference)
//
#include <hip/hip_runtime.h>
#include <math.h>

// Problem constants: C=256, H=W=128, PH=PW=8.
#define C_ 256
#define H_ 128
#define W_ 128
#define PH_ 8
#define PW_ 8
#define HW_ (H_ * W_)

// ---------- Kernel 1: transpose (C, H*W) -> (H*W, C), XCD-affine ----------
// (unchanged: ~10 us, conflict-free, bid&7 = channel group = consuming XCD.)
__global__ __launch_bounds__(256) void transpose_kernel(
    const float* __restrict__ fm, float* __restrict__ fmt)
{
    __shared__ float tile[32 * 257];
    const int tid = threadIdx.x;
    const int g   = blockIdx.x & 7;
    const int hwb = blockIdx.x >> 3;
    const int c0  = g * 32;
    const int hw0 = hwb * 256;

    const int l    = tid & 63;
    const int crow = tid >> 6;
    const int sw   = (l >> 3) & 3;
    #pragma unroll
    for (int k = 0; k < 8; ++k) {
        const int c = crow + 4 * k;
        const float4 v = *(const float4*)(fm + (size_t)(c0 + c) * HW_ + hw0 + 4 * l);
        float* t = tile + c * 257 + 4 * l;
        t[(0 + sw) & 3] = v.x;
        t[(1 + sw) & 3] = v.y;
        t[(2 + sw) & 3] = v.z;
        t[(3 + sw) & 3] = v.w;
    }
    __syncthreads();

    const int cq  = tid & 7;
    const int hwr = tid >> 3;
    #pragma unroll
    for (int m = 0; m < 8; ++m) {
        const int hw = hwr + 32 * m;
        const int o  = (hw & ~3) | (((hw & 3) + m) & 3);
        float4 w;
        w.x = tile[(4 * cq + 0) * 257 + o];
        w.y = tile[(4 * cq + 1) * 257 + o];
        w.z = tile[(4 * cq + 2) * 257 + o];
        w.w = tile[(4 * cq + 3) * 257 + o];
        *(float4*)(fmt + (size_t)(hw0 + hw) * C_ + c0 + 4 * cq) = w;
    }
}

// ---------- Kernel 2: pooling, channel-major ----------
// Block = (n, ph, cg); wave w handles pw in {w, w+4} (setup amortized).
// Lane = 8 position-groups x 8 channel-quads (float4). Unified step loop
// with exact exec-mask predication (col < we): masked lanes issue no L2
// requests. fmax chains shaped for v_max3_f32.
__global__ __launch_bounds__(256) void pool_kernel(
    const float* __restrict__ fmt, const int* __restrict__ rois,
    float* __restrict__ out, int N)
{
    const int bid = blockIdx.x;
    const int cg  = bid & 7;                 // XCD-affine channel group
    const int m   = bid >> 3;
    const int ph  = m & 7;
    const int n   = m >> 3;

    const int wid  = threadIdx.x >> 6;
    const int lane = threadIdx.x & 63;
    const int pg   = lane >> 3;              // position group 0..7
    const int c    = (cg << 5) + ((lane & 7) << 2);

    const int4 roi = ((const int4*)rois)[n];
    const int y = roi.x, x = roi.y, rH = roi.z, rW = roi.w;

    const int hs = (ph * rH) >> 3;
    const int he = ((ph + 1) * rH + 7) >> 3;
    const int nrows = he - hs;               // wave-uniform, 1..17

    const float* rowbase = fmt + ((size_t)(y + hs) * W_ + x) * C_ + c;
    const size_t HSF = (size_t)W_ * C_;      // h stride in floats (128 KB)

    float4 acc[2];

    #pragma unroll
    for (int b = 0; b < 2; ++b) {
        const int pw = wid + 4 * b;          // wave-uniform
        const int ws = (pw * rW) >> 3;
        const int we = ((pw + 1) * rW + 7) >> 3;
        const int nsteps = (we - ws + 7) >> 3;   // 1..3, wave-uniform

        float4 a4 = make_float4(-INFINITY, -INFINITY, -INFINITY, -INFINITY);

        for (int s = 0; s < nsteps; ++s) {
            const int col = ws + 8 * s + pg;
            if (col < we) {                  // exact footprint via exec mask
                const float* p = rowbase + (size_t)col * C_;
                int cnt = nrows;
                while (cnt >= 4) {
                    const float4 v0 = *(const float4*)(p);
                    const float4 v1 = *(const float4*)(p + HSF);
                    const float4 v2 = *(const float4*)(p + 2 * HSF);
                    const float4 v3 = *(const float4*)(p + 3 * HSF);
                    p += 4 * HSF; cnt -= 4;
                    // shaped as max3 pairs: max3(a,b,acc) then max3(t,d,e)
                    a4.x = fmaxf(fmaxf(fmaxf(v0.x, v1.x), a4.x), fmaxf(v2.x, v3.x));
                    a4.y = fmaxf(fmaxf(fmaxf(v0.y, v1.y), a4.y), fmaxf(v2.y, v3.y));
                    a4.z = fmaxf(fmaxf(fmaxf(v0.z, v1.z), a4.z), fmaxf(v2.z, v3.z));
                    a4.w = fmaxf(fmaxf(fmaxf(v0.w, v1.w), a4.w), fmaxf(v2.w, v3.w));
                }
                while (cnt > 0) {
                    const float4 v0 = *(const float4*)(p);
                    p += HSF; --cnt;
                    a4.x = fmaxf(a4.x, v0.x);
                    a4.y = fmaxf(a4.y, v0.y);
                    a4.z = fmaxf(a4.z, v0.z);
                    a4.w = fmaxf(a4.w, v0.w);
                }
            }
        }
        acc[b] = a4;
    }

    // reduce across the 8 position groups (fixed xor swizzles, conflict-free)
    #pragma unroll
    for (int b = 0; b < 2; ++b) {
        #pragma unroll
        for (int mask = 8; mask <= 32; mask <<= 1) {
            acc[b].x = fmaxf(acc[b].x, __shfl_xor(acc[b].x, mask, 64));
            acc[b].y = fmaxf(acc[b].y, __shfl_xor(acc[b].y, mask, 64));
            acc[b].z = fmaxf(acc[b].z, __shfl_xor(acc[b].z, mask, 64));
            acc[b].w = fmaxf(acc[b].w, __shfl_xor(acc[b].w, mask, 64));
        }
    }

    if (lane < 8) {
        float* o = out + ((size_t)n * C_ + c) * (PH_ * PW_) + ph * PW_;
        #pragma unroll
        for (int b = 0; b < 2; ++b) {
            const int pw = wid + 4 * b;
            o[pw]                    = acc[b].x;
            o[pw + PH_ * PW_]        = acc[b].y;
            o[pw + 2 * (PH_ * PW_)]  = acc[b].z;
            o[pw + 3 * (PH_ * PW_)]  = acc[b].w;
        }
    }
}

// ---------- Fallback if ws is too small for the transpose ----------
__global__ __launch_bounds__(256) void roi_pool_fallback(
    const float* __restrict__ fm, const int* __restrict__ rois,
    float* __restrict__ out, int N)
{
    const int wid  = threadIdx.x >> 6;
    const int lane = threadIdx.x & 63;
    const int bid  = blockIdx.x;
    const int xcd  = bid & 7;
    const int t    = bid >> 3;
    const int csub = t & 7;
    const int n    = t >> 3;
    if (n >= N) return;
    const int c = (xcd << 5) + (csub << 2) + wid;

    const int4 roi = ((const int4*)rois)[n];
    const int y = roi.x, x = roi.y, rH = roi.z, rW = roi.w;

    const float2* plane2 = (const float2*)(fm + (size_t)c * (H_ * W_));
    const int pw = lane & 7;
    const int j  = lane >> 3;
    const int ws = (pw * rW) >> 3;
    const int we = (((pw + 1) * rW) + 7) >> 3;

    #pragma unroll
    for (int ph = 0; ph < PH_; ++ph) {
        const int hs = (ph * rH) >> 3;
        const int he = ((ph + 1) * rH + 7) >> 3;
        const float2* p = plane2 + (size_t)(y + hs) * (W_ / 2) + lane;
        float m0 = -INFINITY, m1 = -INFINITY;
        int cnt = he - hs;
        while (cnt >= 2) {
            const float2 a = p[0];
            const float2 b = p[W_ / 2];
            p += W_; cnt -= 2;
            m0 = fmaxf(m0, fmaxf(a.x, b.x));
            m1 = fmaxf(m1, fmaxf(a.y, b.y));
        }
        if (cnt) { const float2 a = p[0]; m0 = fmaxf(m0, a.x); m1 = fmaxf(m1, a.y); }

        float r = -INFINITY;
        #pragma unroll
        for (int k = 0; k < 3; ++k) {
            const int w  = ws + j + k * 8;
            const int wa = x + w;
            const float a = __shfl(m0, (wa >> 1) & 63, 64);
            const float b = __shfl(m1, (wa >> 1) & 63, 64);
            if (w < we) r = fmaxf(r, (wa & 1) ? b : a);
        }
        r = fmaxf(r, __shfl_xor(r, 8, 64));
        r = fmaxf(r, __shfl_xor(r, 16, 64));
        r = fmaxf(r, __shfl_xor(r, 32, 64));
        if (lane < PW_) out[(((size_t)n * C_ + c) * PH_ + ph) * PW_ + lane] = r;
    }
}

extern "C" void kernel_launch(void* const* d_in, const int* in_sizes, int n_in,
                              void* d_out, int out_size, void* d_ws, size_t ws_size,
                              hipStream_t stream) {
    const float* fm   = (const float*)d_in[0];
    const int*   rois = (const int*)d_in[1];
    float*       out  = (float*)d_out;
    const int N = in_sizes[1] / 4;

    const size_t need = (size_t)HW_ * C_ * sizeof(float);
    if (ws_size >= need) {
        float* fmt = (float*)d_ws;
        transpose_kernel<<<dim3((HW_ / 256) * 8), 256, 0, stream>>>(fm, fmt);
        pool_kernel<<<dim3(N * 64), 256, 0, stream>>>(fmt, rois, out, N);
    } else {
        roi_pool_fallback<<<dim3(64 * N), 256, 0, stream>>>(fm, rois, out, N);
    }
}

// Round 9
// 140.336 us; speedup vs baseline: 1.0636x; 1.0636x over previous
//
#include <hip/hip_runtime.h>
#include <math.h>

// Problem constants: C=256, H=W=128, PH=PW=8.
#define C_ 256
#define H_ 128
#define W_ 128
#define PH_ 8
#define PW_ 8
#define HW_ (H_ * W_)

typedef unsigned short u16;
typedef u16 u16x4 __attribute__((ext_vector_type(4)));
typedef u16 u16x8 __attribute__((ext_vector_type(8)));

// fp32 -> bf16 (RNE) -> monotone-mapped u16 key (unsigned order == float order)
__device__ __forceinline__ u16 f32_to_key(float f) {
    unsigned u = __float_as_uint(f);
    unsigned r = (u + 0x7fffu + ((u >> 16) & 1u)) >> 16;   // RNE to bf16
    u16 b = (u16)r;
    return (b & 0x8000u) ? (u16)~b : (u16)(b | 0x8000u);
}
__device__ __forceinline__ float key_to_f32(u16 k) {
    u16 b = (k & 0x8000u) ? (u16)(k & 0x7fffu) : (u16)~k;
    return __uint_as_float(((unsigned)b) << 16);
}

// ---------- Kernel 1: transpose (C,H*W) fp32 -> (H*W,C) u16-key, XCD-affine ----
// Same structure as the proven R4 transpose (conflict-free, bid&7 = channel
// group = consuming XCD); only the write stage converts to u16 keys (8 B/lane).
__global__ __launch_bounds__(256) void transpose_kernel(
    const float* __restrict__ fm, u16* __restrict__ fmt)
{
    __shared__ float tile[32 * 257];
    const int tid = threadIdx.x;
    const int g   = blockIdx.x & 7;
    const int hwb = blockIdx.x >> 3;
    const int c0  = g * 32;
    const int hw0 = hwb * 256;

    const int l    = tid & 63;
    const int crow = tid >> 6;
    const int sw   = (l >> 3) & 3;
    #pragma unroll
    for (int k = 0; k < 8; ++k) {
        const int c = crow + 4 * k;
        const float4 v = *(const float4*)(fm + (size_t)(c0 + c) * HW_ + hw0 + 4 * l);
        float* t = tile + c * 257 + 4 * l;
        t[(0 + sw) & 3] = v.x;
        t[(1 + sw) & 3] = v.y;
        t[(2 + sw) & 3] = v.z;
        t[(3 + sw) & 3] = v.w;
    }
    __syncthreads();

    const int cq  = tid & 7;
    const int hwr = tid >> 3;
    #pragma unroll
    for (int m = 0; m < 8; ++m) {
        const int hw = hwr + 32 * m;
        const int o  = (hw & ~3) | (((hw & 3) + m) & 3);
        u16x4 w;
        w.x = f32_to_key(tile[(4 * cq + 0) * 257 + o]);
        w.y = f32_to_key(tile[(4 * cq + 1) * 257 + o]);
        w.z = f32_to_key(tile[(4 * cq + 2) * 257 + o]);
        w.w = f32_to_key(tile[(4 * cq + 3) * 257 + o]);
        *(u16x4*)(fmt + (size_t)(hw0 + hw) * C_ + c0 + 4 * cq) = w;
    }
}

// ---------- Kernel 2: pool on u16 keys, channel-major ----------
// Wave = (n, pw, cg): all 8 ph bins per wave (prologue amortized 8x).
// Lane = 16 position-groups x 4 channel-octs (u16x8 = 16 B = 8 channels).
// nsteps = ceil(bw/16) (1, rarely 2); exact footprint via exec mask.
// Reduction: packed u16 max (v_pk_max_u16) + 4-level xor shuffle.
__global__ __launch_bounds__(256) void pool_kernel(
    const u16* __restrict__ fmt, const int* __restrict__ rois,
    float* __restrict__ out, int N)
{
    const int bid  = blockIdx.x;
    const int cg   = bid & 7;            // XCD-affine channel group
    const int r    = bid >> 3;
    const int half = r & 1;
    const int n    = r >> 1;

    const int wid  = threadIdx.x >> 6;
    const int lane = threadIdx.x & 63;
    const int pw   = half * 4 + wid;     // wave-uniform
    const int pg   = lane >> 2;          // position group 0..15
    const int c    = (cg << 5) + ((lane & 3) << 3);  // 8-channel base

    const int4 roi = ((const int4*)rois)[n];
    const int y = roi.x, x = roi.y, rH = roi.z, rW = roi.w;

    const int ws = (pw * rW) >> 3;
    const int we = ((pw + 1) * rW + 7) >> 3;
    const int bw = we - ws;              // 1..17
    const int nsteps = (bw + 15) >> 4;   // 1 or 2 (wave-uniform)

    const size_t HS = (size_t)W_ * C_;   // row stride in u16 elements

    #pragma unroll
    for (int ph = 0; ph < PH_; ++ph) {
        const int hs = (ph * rH) >> 3;
        const int he = ((ph + 1) * rH + 7) >> 3;

        u16x8 acc = {0, 0, 0, 0, 0, 0, 0, 0};   // minimum key

        for (int s = 0; s < nsteps; ++s) {
            const int col = ws + 16 * s + pg;
            if (col < we) {              // exec-masked: no L2 traffic if off
                const u16* p = fmt + ((size_t)(y + hs) * W_ + x + col) * C_ + c;
                int cnt = he - hs;
                while (cnt >= 4) {
                    u16x8 v0 = *(const u16x8*)(p);
                    u16x8 v1 = *(const u16x8*)(p + HS);
                    u16x8 v2 = *(const u16x8*)(p + 2 * HS);
                    u16x8 v3 = *(const u16x8*)(p + 3 * HS);
                    p += 4 * HS; cnt -= 4;
                    v0  = __builtin_elementwise_max(v0, v1);
                    v2  = __builtin_elementwise_max(v2, v3);
                    acc = __builtin_elementwise_max(acc,
                            __builtin_elementwise_max(v0, v2));
                }
                while (cnt > 0) {
                    u16x8 v0 = *(const u16x8*)(p);
                    p += HS; --cnt;
                    acc = __builtin_elementwise_max(acc, v0);
                }
            }
        }

        // reduce across the 16 position groups (xor 4,8,16,32 on 4 dwords)
        union U { u16x8 v; unsigned u[4]; };
        U a; a.v = acc;
        #pragma unroll
        for (int mask = 4; mask <= 32; mask <<= 1) {
            U t;
            #pragma unroll
            for (int i = 0; i < 4; ++i) t.u[i] = __shfl_xor(a.u[i], mask, 64);
            a.v = __builtin_elementwise_max(a.v, t.v);
        }

        if (pg == 0) {   // 4 lanes: each writes its 8 channels
            float* o = out + ((size_t)n * C_ + c) * (PH_ * PW_) + ph * PW_ + pw;
            #pragma unroll
            for (int i = 0; i < 8; ++i)
                o[(size_t)i * (PH_ * PW_)] = key_to_f32(a.v[i]);
        }
    }
}

// ---------- Fallback if ws is too small ----------
__global__ __launch_bounds__(256) void roi_pool_fallback(
    const float* __restrict__ fm, const int* __restrict__ rois,
    float* __restrict__ out, int N)
{
    const int wid  = threadIdx.x >> 6;
    const int lane = threadIdx.x & 63;
    const int bid  = blockIdx.x;
    const int xcd  = bid & 7;
    const int t    = bid >> 3;
    const int csub = t & 7;
    const int n    = t >> 3;
    if (n >= N) return;
    const int c = (xcd << 5) + (csub << 2) + wid;

    const int4 roi = ((const int4*)rois)[n];
    const int y = roi.x, x = roi.y, rH = roi.z, rW = roi.w;

    const float2* plane2 = (const float2*)(fm + (size_t)c * (H_ * W_));
    const int pw = lane & 7;
    const int j  = lane >> 3;
    const int ws = (pw * rW) >> 3;
    const int we = (((pw + 1) * rW) + 7) >> 3;

    #pragma unroll
    for (int ph = 0; ph < PH_; ++ph) {
        const int hs = (ph * rH) >> 3;
        const int he = ((ph + 1) * rH + 7) >> 3;
        const float2* p = plane2 + (size_t)(y + hs) * (W_ / 2) + lane;
        float m0 = -INFINITY, m1 = -INFINITY;
        int cnt = he - hs;
        while (cnt >= 2) {
            const float2 a = p[0];
            const float2 b = p[W_ / 2];
            p += W_; cnt -= 2;
            m0 = fmaxf(m0, fmaxf(a.x, b.x));
            m1 = fmaxf(m1, fmaxf(a.y, b.y));
        }
        if (cnt) { const float2 a = p[0]; m0 = fmaxf(m0, a.x); m1 = fmaxf(m1, a.y); }

        float rr = -INFINITY;
        #pragma unroll
        for (int k = 0; k < 3; ++k) {
            const int w  = ws + j + k * 8;
            const int wa = x + w;
            const float a = __shfl(m0, (wa >> 1) & 63, 64);
            const float b = __shfl(m1, (wa >> 1) & 63, 64);
            if (w < we) rr = fmaxf(rr, (wa & 1) ? b : a);
        }
        rr = fmaxf(rr, __shfl_xor(rr, 8, 64));
        rr = fmaxf(rr, __shfl_xor(rr, 16, 64));
        rr = fmaxf(rr, __shfl_xor(rr, 32, 64));
        if (lane < PW_) out[(((size_t)n * C_ + c) * PH_ + ph) * PW_ + lane] = rr;
    }
}

extern "C" void kernel_launch(void* const* d_in, const int* in_sizes, int n_in,
                              void* d_out, int out_size, void* d_ws, size_t ws_size,
                              hipStream_t stream) {
    const float* fm   = (const float*)d_in[0];
    const int*   rois = (const int*)d_in[1];
    float*       out  = (float*)d_out;
    const int N = in_sizes[1] / 4;

    const size_t need = (size_t)HW_ * C_ * sizeof(u16);
    if (ws_size >= need) {
        u16* fmt = (u16*)d_ws;
        transpose_kernel<<<dim3((HW_ / 256) * 8), 256, 0, stream>>>(fm, fmt);
        pool_kernel<<<dim3(N * 2 * 8), 256, 0, stream>>>(fmt, rois, out, N);
    } else {
        roi_pool_fallback<<<dim3(64 * N), 256, 0, stream>>>(fm, rois, out, N);
    }
}

// Round 10
// 136.715 us; speedup vs baseline: 1.0918x; 1.0265x over previous
//
#include <hip/hip_runtime.h>
#include <math.h>

// Problem constants: C=256, H=W=128, PH=PW=8.
#define C_ 256
#define H_ 128
#define W_ 128
#define PH_ 8
#define PW_ 8
#define HW_ (H_ * W_)

typedef unsigned short u16;
typedef u16 u16x4 __attribute__((ext_vector_type(4)));
typedef u16 u16x8 __attribute__((ext_vector_type(8)));

// fp32 -> bf16 (RNE) -> monotone-mapped u16 key (unsigned order == float order)
__device__ __forceinline__ u16 f32_to_key(float f) {
    unsigned u = __float_as_uint(f);
    unsigned r = (u + 0x7fffu + ((u >> 16) & 1u)) >> 16;   // RNE to bf16
    u16 b = (u16)r;
    return (b & 0x8000u) ? (u16)~b : (u16)(b | 0x8000u);
}
__device__ __forceinline__ float key_to_f32(u16 k) {
    u16 b = (k & 0x8000u) ? (u16)(k & 0x7fffu) : (u16)~k;
    return __uint_as_float(((unsigned)b) << 16);
}

// ---------- Kernel 1: (C,H*W) fp32 -> blocked (8 cg, H*W, 32ch) u16-key ----------
// bid&7 = cg = consuming XCD (XCD-affine). Per (cg,hw) the 32 channels are
// contiguous 64 B -> pool loads of consecutive positions are fully dense.
__global__ __launch_bounds__(256) void transpose_kernel(
    const float* __restrict__ fm, u16* __restrict__ fmt)
{
    __shared__ float tile[32 * 257];
    const int tid = threadIdx.x;
    const int g   = blockIdx.x & 7;
    const int hwb = blockIdx.x >> 3;
    const int c0  = g * 32;
    const int hw0 = hwb * 256;

    const int l    = tid & 63;
    const int crow = tid >> 6;
    const int sw   = (l >> 3) & 3;
    #pragma unroll
    for (int k = 0; k < 8; ++k) {
        const int c = crow + 4 * k;
        const float4 v = *(const float4*)(fm + (size_t)(c0 + c) * HW_ + hw0 + 4 * l);
        float* t = tile + c * 257 + 4 * l;
        t[(0 + sw) & 3] = v.x;
        t[(1 + sw) & 3] = v.y;
        t[(2 + sw) & 3] = v.z;
        t[(3 + sw) & 3] = v.w;
    }
    __syncthreads();

    // blocked destination: fmt[g][hw][cl], cl = 4*cq .. 4*cq+3
    u16* dst = fmt + (size_t)g * HW_ * 32;
    const int cq  = tid & 7;
    const int hwr = tid >> 3;
    #pragma unroll
    for (int m = 0; m < 8; ++m) {
        const int hw = hwr + 32 * m;
        const int o  = (hw & ~3) | (((hw & 3) + m) & 3);
        u16x4 w;
        w.x = f32_to_key(tile[(4 * cq + 0) * 257 + o]);
        w.y = f32_to_key(tile[(4 * cq + 1) * 257 + o]);
        w.z = f32_to_key(tile[(4 * cq + 2) * 257 + o]);
        w.w = f32_to_key(tile[(4 * cq + 3) * 257 + o]);
        *(u16x4*)(dst + (size_t)(hw0 + hw) * 32 + 4 * cq) = w;
    }
}

// ---------- Kernel 2: pool on u16 keys, blocked layout ----------
// Wave = (n, pw, cg): all 8 ph bins per wave. Lane = 16 position-groups x
// 4 channel-octs (u16x8). With the blocked layout one wave-load covers 16
// consecutive positions x 32 ch = contiguous, fully-used lines; masked tail
// lanes (col >= we) issue nothing -> exact footprint.
__global__ __launch_bounds__(256) void pool_kernel(
    const u16* __restrict__ fmt, const int* __restrict__ rois,
    float* __restrict__ out, int N)
{
    const int bid  = blockIdx.x;
    const int cg   = bid & 7;            // XCD-affine channel group
    const int r    = bid >> 3;
    const int half = r & 1;
    const int n    = r >> 1;

    const int wid  = threadIdx.x >> 6;
    const int lane = threadIdx.x & 63;
    const int pw   = half * 4 + wid;     // wave-uniform
    const int pg   = lane >> 2;          // position group 0..15
    const int co   = (lane & 3) << 3;    // channel offset within the 32: 0,8,16,24

    const int4 roi = ((const int4*)rois)[n];
    const int y = roi.x, x = roi.y, rH = roi.z, rW = roi.w;

    const int ws = (pw * rW) >> 3;
    const int we = ((pw + 1) * rW + 7) >> 3;
    const int bw = we - ws;              // 1..17
    const int nsteps = (bw + 15) >> 4;   // 1 or 2 (wave-uniform)

    const u16* plane = fmt + (size_t)cg * HW_ * 32;
    const size_t HS = (size_t)W_ * 32;   // row stride in u16 elements (8 KB)

    #pragma unroll
    for (int ph = 0; ph < PH_; ++ph) {
        const int hs = (ph * rH) >> 3;
        const int he = ((ph + 1) * rH + 7) >> 3;

        u16x8 acc = {0, 0, 0, 0, 0, 0, 0, 0};   // minimum key

        for (int s = 0; s < nsteps; ++s) {
            const int col = ws + 16 * s + pg;
            if (col < we) {              // exec-masked: no traffic if off
                const u16* p = plane + ((size_t)(y + hs) * W_ + x + col) * 32 + co;
                int cnt = he - hs;
                while (cnt >= 4) {
                    u16x8 v0 = *(const u16x8*)(p);
                    u16x8 v1 = *(const u16x8*)(p + HS);
                    u16x8 v2 = *(const u16x8*)(p + 2 * HS);
                    u16x8 v3 = *(const u16x8*)(p + 3 * HS);
                    p += 4 * HS; cnt -= 4;
                    v0  = __builtin_elementwise_max(v0, v1);
                    v2  = __builtin_elementwise_max(v2, v3);
                    acc = __builtin_elementwise_max(acc,
                            __builtin_elementwise_max(v0, v2));
                }
                while (cnt > 0) {
                    u16x8 v0 = *(const u16x8*)(p);
                    p += HS; --cnt;
                    acc = __builtin_elementwise_max(acc, v0);
                }
            }
        }

        // reduce across the 16 position groups (xor 4,8,16,32 on 4 dwords)
        union U { u16x8 v; unsigned u[4]; };
        U a; a.v = acc;
        #pragma unroll
        for (int mask = 4; mask <= 32; mask <<= 1) {
            U t;
            #pragma unroll
            for (int i = 0; i < 4; ++i) t.u[i] = __shfl_xor(a.u[i], mask, 64);
            a.v = __builtin_elementwise_max(a.v, t.v);
        }

        if (pg == 0) {   // 4 lanes: each writes its 8 channels
            const int c = (cg << 5) + co;
            float* o = out + ((size_t)n * C_ + c) * (PH_ * PW_) + ph * PW_ + pw;
            #pragma unroll
            for (int i = 0; i < 8; ++i)
                o[(size_t)i * (PH_ * PW_)] = key_to_f32(a.v[i]);
        }
    }
}

// ---------- Fallback if ws is too small ----------
__global__ __launch_bounds__(256) void roi_pool_fallback(
    const float* __restrict__ fm, const int* __restrict__ rois,
    float* __restrict__ out, int N)
{
    const int wid  = threadIdx.x >> 6;
    const int lane = threadIdx.x & 63;
    const int bid  = blockIdx.x;
    const int xcd  = bid & 7;
    const int t    = bid >> 3;
    const int csub = t & 7;
    const int n    = t >> 3;
    if (n >= N) return;
    const int c = (xcd << 5) + (csub << 2) + wid;

    const int4 roi = ((const int4*)rois)[n];
    const int y = roi.x, x = roi.y, rH = roi.z, rW = roi.w;

    const float2* plane2 = (const float2*)(fm + (size_t)c * (H_ * W_));
    const int pw = lane & 7;
    const int j  = lane >> 3;
    const int ws = (pw * rW) >> 3;
    const int we = (((pw + 1) * rW) + 7) >> 3;

    #pragma unroll
    for (int ph = 0; ph < PH_; ++ph) {
        const int hs = (ph * rH) >> 3;
        const int he = ((ph + 1) * rH + 7) >> 3;
        const float2* p = plane2 + (size_t)(y + hs) * (W_ / 2) + lane;
        float m0 = -INFINITY, m1 = -INFINITY;
        int cnt = he - hs;
        while (cnt >= 2) {
            const float2 a = p[0];
            const float2 b = p[W_ / 2];
            p += W_; cnt -= 2;
            m0 = fmaxf(m0, fmaxf(a.x, b.x));
            m1 = fmaxf(m1, fmaxf(a.y, b.y));
        }
        if (cnt) { const float2 a = p[0]; m0 = fmaxf(m0, a.x); m1 = fmaxf(m1, a.y); }

        float rr = -INFINITY;
        #pragma unroll
        for (int k = 0; k < 3; ++k) {
            const int w  = ws + j + k * 8;
            const int wa = x + w;
            const float a = __shfl(m0, (wa >> 1) & 63, 64);
            const float b = __shfl(m1, (wa >> 1) & 63, 64);
            if (w < we) rr = fmaxf(rr, (wa & 1) ? b : a);
        }
        rr = fmaxf(rr, __shfl_xor(rr, 8, 64));
        rr = fmaxf(rr, __shfl_xor(rr, 16, 64));
        rr = fmaxf(rr, __shfl_xor(rr, 32, 64));
        if (lane < PW_) out[(((size_t)n * C_ + c) * PH_ + ph) * PW_ + lane] = rr;
    }
}

extern "C" void kernel_launch(void* const* d_in, const int* in_sizes, int n_in,
                              void* d_out, int out_size, void* d_ws, size_t ws_size,
                              hipStream_t stream) {
    const float* fm   = (const float*)d_in[0];
    const int*   rois = (const int*)d_in[1];
    float*       out  = (float*)d_out;
    const int N = in_sizes[1] / 4;

    const size_t need = (size_t)HW_ * C_ * sizeof(u16);
    if (ws_size >= need) {
        u16* fmt = (u16*)d_ws;
        transpose_kernel<<<dim3((HW_ / 256) * 8), 256, 0, stream>>>(fm, fmt);
        pool_kernel<<<dim3(N * 2 * 8), 256, 0, stream>>>(fmt, rois, out, N);
    } else {
        roi_pool_fallback<<<dim3(64 * N), 256, 0, stream>>>(fm, rois, out, N);
    }
}

// Round 11
// 123.068 us; speedup vs baseline: 1.2128x; 1.1109x over previous
//
#include <hip/hip_runtime.h>
#include <math.h>

// Problem constants: C=256, H=W=128, PH=PW=8.
#define C_ 256
#define H_ 128
#define W_ 128
#define PH_ 8
#define PW_ 8
#define HW_ (H_ * W_)

typedef unsigned short u16;
typedef u16 u16x4 __attribute__((ext_vector_type(4)));
typedef u16 u16x8 __attribute__((ext_vector_type(8)));

__device__ __forceinline__ u16x8 kmax(u16x8 a, u16x8 b) {
    return __builtin_elementwise_max(a, b);
}

// fp32 -> bf16 (RNE) -> monotone-mapped u16 key (unsigned order == float order)
__device__ __forceinline__ u16 f32_to_key(float f) {
    unsigned u = __float_as_uint(f);
    unsigned r = (u + 0x7fffu + ((u >> 16) & 1u)) >> 16;   // RNE to bf16
    u16 b = (u16)r;
    return (b & 0x8000u) ? (u16)~b : (u16)(b | 0x8000u);
}
__device__ __forceinline__ float key_to_f32(u16 k) {
    u16 b = (k & 0x8000u) ? (u16)(k & 0x7fffu) : (u16)~k;
    return __uint_as_float(((unsigned)b) << 16);
}

// ---------- Kernel 1: (C,H*W) fp32 -> blocked u16 keys + row-pair-max plane ----
// fmt:  (8 cg, H*W, 32ch)    full-res keys
// pmax: (8 cg, H/2*W, 32ch)  max over row pairs {2k, 2k+1}
// Each block holds exactly rows {2*hwb, 2*hwb+1} (hw0=256-aligned, W=128), so
// the pair-max is computed from the LDS tile for free. bid&7 = cg = consuming XCD.
__global__ __launch_bounds__(256) void transpose_kernel(
    const float* __restrict__ fm, u16* __restrict__ fmt, u16* __restrict__ pmax)
{
    __shared__ float tile[32 * 257];
    const int tid = threadIdx.x;
    const int g   = blockIdx.x & 7;
    const int hwb = blockIdx.x >> 3;
    const int c0  = g * 32;
    const int hw0 = hwb * 256;

    const int l    = tid & 63;
    const int crow = tid >> 6;
    const int sw   = (l >> 3) & 3;
    #pragma unroll
    for (int k = 0; k < 8; ++k) {
        const int c = crow + 4 * k;
        const float4 v = *(const float4*)(fm + (size_t)(c0 + c) * HW_ + hw0 + 4 * l);
        float* t = tile + c * 257 + 4 * l;
        t[(0 + sw) & 3] = v.x;
        t[(1 + sw) & 3] = v.y;
        t[(2 + sw) & 3] = v.z;
        t[(3 + sw) & 3] = v.w;
    }
    __syncthreads();

    u16* dst = fmt + (size_t)g * HW_ * 32;
    const int cq  = tid & 7;
    const int hwr = tid >> 3;
    #pragma unroll
    for (int m = 0; m < 8; ++m) {
        const int hw = hwr + 32 * m;
        const int o  = (hw & ~3) | (((hw & 3) + m) & 3);
        u16x4 w;
        w.x = f32_to_key(tile[(4 * cq + 0) * 257 + o]);
        w.y = f32_to_key(tile[(4 * cq + 1) * 257 + o]);
        w.z = f32_to_key(tile[(4 * cq + 2) * 257 + o]);
        w.w = f32_to_key(tile[(4 * cq + 3) * 257 + o]);
        *(u16x4*)(dst + (size_t)(hw0 + hw) * 32 + 4 * cq) = w;
    }

    // pair-max over rows h0=2*hwb (hw<128) and h0+1 (hw+128): o(hw+128)=o(hw)+128
    u16* pdst = pmax + (size_t)g * (HW_ / 2) * 32;
    #pragma unroll
    for (int m = 0; m < 4; ++m) {
        const int w_ = hwr + 32 * m;                      // 0..127
        const int o  = (w_ & ~3) | (((w_ & 3) + m) & 3);
        u16x4 v;
        v.x = f32_to_key(fmaxf(tile[(4 * cq + 0) * 257 + o],
                               tile[(4 * cq + 0) * 257 + o + 128]));
        v.y = f32_to_key(fmaxf(tile[(4 * cq + 1) * 257 + o],
                               tile[(4 * cq + 1) * 257 + o + 128]));
        v.z = f32_to_key(fmaxf(tile[(4 * cq + 2) * 257 + o],
                               tile[(4 * cq + 2) * 257 + o + 128]));
        v.w = f32_to_key(fmaxf(tile[(4 * cq + 3) * 257 + o],
                               tile[(4 * cq + 3) * 257 + o + 128]));
        *(u16x4*)(pdst + ((size_t)hwb * W_ + w_) * 32 + 4 * cq) = v;
    }
}

// ---------- Kernel 2: pool on u16 keys via pair-max + edge rows ----------
// Wave = (n, pw, cg), all 8 ph bins. Lane = 16 position-groups x 4 channel-octs.
// Per bin: rows [a,b) = (a&1 ? edge a) + pairs [k0,k1) from pmax + (b&1 ? edge b-1),
// loaded as ONE independent burst (pair loads clamped to last -> same hot line,
// no extra bytes) -> single vmcnt wait region per bin.
__global__ __launch_bounds__(256) void pool_kernel(
    const u16* __restrict__ fmt, const u16* __restrict__ pmax,
    const int* __restrict__ rois, float* __restrict__ out, int N)
{
    const int bid  = blockIdx.x;
    const int cg   = bid & 7;            // XCD-affine channel group
    const int r    = bid >> 3;
    const int half = r & 1;
    const int n    = r >> 1;

    const int wid  = threadIdx.x >> 6;
    const int lane = threadIdx.x & 63;
    const int pw   = half * 4 + wid;     // wave-uniform
    const int pg   = lane >> 2;          // position group 0..15
    const int co   = (lane & 3) << 3;    // channel offset: 0,8,16,24

    const int4 roi = ((const int4*)rois)[n];
    const int y = roi.x, x = roi.y, rH = roi.z, rW = roi.w;

    const int ws = (pw * rW) >> 3;
    const int we = ((pw + 1) * rW + 7) >> 3;
    const int bw = we - ws;              // 1..17
    const int nsteps = (bw + 15) >> 4;   // 1 or 2 (wave-uniform)

    const u16* plane  = fmt  + (size_t)cg * HW_ * 32;
    const u16* pplane = pmax + (size_t)cg * (HW_ / 2) * 32;
    const size_t RS = (size_t)W_ * 32;   // row stride in u16 (both arrays)

    #pragma unroll
    for (int ph = 0; ph < PH_; ++ph) {
        const int hs = (ph * rH) >> 3;
        const int he = ((ph + 1) * rH + 7) >> 3;
        const int a  = y + hs;           // first row (absolute)
        const int b  = y + he;           // last row + 1 (absolute)
        const int k0 = (a + 1) >> 1;     // first full pair
        const int k1 = b >> 1;           // one past last full pair
        const int np = k1 - k0;          // 0..8, wave-uniform

        u16x8 acc = {0, 0, 0, 0, 0, 0, 0, 0};   // minimum key

        for (int s = 0; s < nsteps; ++s) {
            const int col = ws + 16 * s + pg;
            if (col < we) {              // exec-masked: no traffic if off
                const size_t cofs = (size_t)(x + col) * 32 + co;
                if (a & 1)
                    acc = kmax(acc, *(const u16x8*)(plane + (size_t)a * RS + cofs));
                if (b & 1)
                    acc = kmax(acc, *(const u16x8*)(plane + (size_t)(b - 1) * RS + cofs));
                if (np > 0) {
                    const u16* pp = pplane + (size_t)k0 * RS + cofs;
                    const int last = np - 1;
                    if (np <= 4) {
                        u16x8 t0 = *(const u16x8*)(pp);
                        u16x8 t1 = *(const u16x8*)(pp + (size_t)min(1, last) * RS);
                        u16x8 t2 = *(const u16x8*)(pp + (size_t)min(2, last) * RS);
                        u16x8 t3 = *(const u16x8*)(pp + (size_t)min(3, last) * RS);
                        acc = kmax(acc, kmax(kmax(t0, t1), kmax(t2, t3)));
                    } else {
                        u16x8 t0 = *(const u16x8*)(pp);
                        u16x8 t1 = *(const u16x8*)(pp + RS);
                        u16x8 t2 = *(const u16x8*)(pp + 2 * RS);
                        u16x8 t3 = *(const u16x8*)(pp + 3 * RS);
                        u16x8 t4 = *(const u16x8*)(pp + 4 * RS);
                        u16x8 t5 = *(const u16x8*)(pp + (size_t)min(5, last) * RS);
                        u16x8 t6 = *(const u16x8*)(pp + (size_t)min(6, last) * RS);
                        u16x8 t7 = *(const u16x8*)(pp + (size_t)min(7, last) * RS);
                        t0 = kmax(t0, t1); t2 = kmax(t2, t3);
                        t4 = kmax(t4, t5); t6 = kmax(t6, t7);
                        acc = kmax(acc, kmax(kmax(t0, t2), kmax(t4, t6)));
                    }
                }
            }
        }

        // reduce across the 16 position groups (xor 4..32 on 4 dwords)
        union U { u16x8 v; unsigned u[4]; };
        U aa; aa.v = acc;
        #pragma unroll
        for (int mask = 4; mask <= 32; mask <<= 1) {
            U t;
            #pragma unroll
            for (int i = 0; i < 4; ++i) t.u[i] = __shfl_xor(aa.u[i], mask, 64);
            aa.v = __builtin_elementwise_max(aa.v, t.v);
        }

        if (pg == 0) {   // 4 lanes: each writes its 8 channels
            const int c = (cg << 5) + co;
            float* o = out + ((size_t)n * C_ + c) * (PH_ * PW_) + ph * PW_ + pw;
            #pragma unroll
            for (int i = 0; i < 8; ++i)
                o[(size_t)i * (PH_ * PW_)] = key_to_f32(aa.v[i]);
        }
    }
}

// ---------- Fallback if ws is too small ----------
__global__ __launch_bounds__(256) void roi_pool_fallback(
    const float* __restrict__ fm, const int* __restrict__ rois,
    float* __restrict__ out, int N)
{
    const int wid  = threadIdx.x >> 6;
    const int lane = threadIdx.x & 63;
    const int bid  = blockIdx.x;
    const int xcd  = bid & 7;
    const int t    = bid >> 3;
    const int csub = t & 7;
    const int n    = t >> 3;
    if (n >= N) return;
    const int c = (xcd << 5) + (csub << 2) + wid;

    const int4 roi = ((const int4*)rois)[n];
    const int y = roi.x, x = roi.y, rH = roi.z, rW = roi.w;

    const float2* plane2 = (const float2*)(fm + (size_t)c * (H_ * W_));
    const int pw = lane & 7;
    const int j  = lane >> 3;
    const int ws = (pw * rW) >> 3;
    const int we = (((pw + 1) * rW) + 7) >> 3;

    #pragma unroll
    for (int ph = 0; ph < PH_; ++ph) {
        const int hs = (ph * rH) >> 3;
        const int he = ((ph + 1) * rH + 7) >> 3;
        const float2* p = plane2 + (size_t)(y + hs) * (W_ / 2) + lane;
        float m0 = -INFINITY, m1 = -INFINITY;
        int cnt = he - hs;
        while (cnt >= 2) {
            const float2 a = p[0];
            const float2 b = p[W_ / 2];
            p += W_; cnt -= 2;
            m0 = fmaxf(m0, fmaxf(a.x, b.x));
            m1 = fmaxf(m1, fmaxf(a.y, b.y));
        }
        if (cnt) { const float2 a = p[0]; m0 = fmaxf(m0, a.x); m1 = fmaxf(m1, a.y); }

        float rr = -INFINITY;
        #pragma unroll
        for (int k = 0; k < 3; ++k) {
            const int w  = ws + j + k * 8;
            const int wa = x + w;
            const float a = __shfl(m0, (wa >> 1) & 63, 64);
            const float b = __shfl(m1, (wa >> 1) & 63, 64);
            if (w < we) rr = fmaxf(rr, (wa & 1) ? b : a);
        }
        rr = fmaxf(rr, __shfl_xor(rr, 8, 64));
        rr = fmaxf(rr, __shfl_xor(rr, 16, 64));
        rr = fmaxf(rr, __shfl_xor(rr, 32, 64));
        if (lane < PW_) out[(((size_t)n * C_ + c) * PH_ + ph) * PW_ + lane] = rr;
    }
}

extern "C" void kernel_launch(void* const* d_in, const int* in_sizes, int n_in,
                              void* d_out, int out_size, void* d_ws, size_t ws_size,
                              hipStream_t stream) {
    const float* fm   = (const float*)d_in[0];
    const int*   rois = (const int*)d_in[1];
    float*       out  = (float*)d_out;
    const int N = in_sizes[1] / 4;

    const size_t fmt_bytes  = (size_t)HW_ * C_ * sizeof(u16);       // 8.39 MB
    const size_t pmax_bytes = (size_t)(HW_ / 2) * C_ * sizeof(u16); // 4.19 MB
    if (ws_size >= fmt_bytes + pmax_bytes) {
        u16* fmt = (u16*)d_ws;
        u16* pmx = (u16*)((char*)d_ws + fmt_bytes);
        transpose_kernel<<<dim3((HW_ / 256) * 8), 256, 0, stream>>>(fm, fmt, pmx);
        pool_kernel<<<dim3(N * 2 * 8), 256, 0, stream>>>(fmt, pmx, rois, out, N);
    } else {
        roi_pool_fallback<<<dim3(64 * N), 256, 0, stream>>>(fm, rois, out, N);
    }
}